// Round 14
// baseline (68.381 us; speedup 1.0000x reference)
//
#include <hip/hip_runtime.h>
#include <math.h>

#define BB 2
#define CC 16
#define HH 32
#define WW 32
#define NN (HH*WW)
#define NPX (BB*NN)        // 2048 pixels
#define PH  512            // k-records per LDS phase

typedef _Float16 half2_t __attribute__((ext_vector_type(2)));

__device__ __forceinline__ float h2f_dot(float packed_a, half2_t b, float c) {
    half2_t a = __builtin_bit_cast(half2_t, packed_a);
#if __has_builtin(__builtin_amdgcn_fdot2)
    return __builtin_amdgcn_fdot2(a, b, c, false);
#else
    return c + (float)a.x*(float)b.x + (float)a.y*(float)b.y;
#endif
}

// ---------------------------------------------------------------------------
// Single kernel: 1024 blocks x 256 thr (4 waves) = 4 blocks/CU (36.4 KB LDS).
// Block owns 2 pixels; wave wv -> pixel (wv>>1), k-chunk (wv&1).
// Two phases of 512 k-records: redundant per-block fill (coalesced global,
// f16-compressed embeddings) -> sync -> each wave accumulates its pixel over
// its 256-record chunk (linear conflict-free ds_read_b128, fdot2 affinity)
// -> sync. Butterfly(26) -> LDS combine chunk pairs -> 2 solver threads.
// ---------------------------------------------------------------------------
__global__ __launch_bounds__(256, 4)
void dse3_mono2(const float* __restrict__ emb,
                const float* __restrict__ rev,
                const float* __restrict__ wgt,
                const float* __restrict__ dep,
                const float* __restrict__ pix,
                const float* __restrict__ Tm,
                float* __restrict__ out)
{
    __shared__ float4 sE4[PH*2];        // 16 KB: 16 halves per record
    __shared__ float4 sQ0[PH];          //  8 KB: X, Y, Z, p0
    __shared__ float4 sQ1[PH];          //  8 KB: p1, p2, w0, w1
    __shared__ float2 sQ2[PH];          //  4 KB: w2, |e|^2 (rounded)
    __shared__ float  ldsR[4][26];

    int tid  = threadIdx.x;
    int lane = tid & 63;
    int wv   = tid >> 6;
    int s    = wv >> 1;                 // pixel slot in block
    int h    = wv & 1;                  // k-chunk within phase
    int px   = blockIdx.x * 2 + s;
    int b    = px >> 10;
    int kpx  = px & (NN - 1);

    float fx = pix[b*16 + 0], fy = pix[b*16 + 5];
    float x0 = pix[b*16 + 2], y0 = pix[b*16 + 6];
    float ifx = __builtin_amdgcn_rcpf(fx);
    float ify = __builtin_amdgcn_rcpf(fy);

    // ---- own pixel embedding (f16-rounded, consistent with LDS records) ----
    half2_t eih[8];
    float sei = 0.f;
    #pragma unroll
    for (int c = 0; c < 8; ++c) {
        float f0 = emb[(size_t)b*CC*NN + (size_t)(2*c  )*NN + kpx];
        float f1 = emb[(size_t)b*CC*NN + (size_t)(2*c+1)*NN + kpx];
        half2_t hp; hp.x = (_Float16)f0; hp.y = (_Float16)f1;
        eih[c] = hp;
        float r0 = (float)hp.x, r1 = (float)hp.y;
        sei += r0*r0 + r1*r1;
    }
    const float4* Tp4 = (const float4*)(Tm + (size_t)px * 16);
    float4 Tr0 = Tp4[0], Tr1 = Tp4[1], Tr2 = Tp4[2];

    // ---- accumulators (M-factorized, 26) ----
    float aM0=0.f, aM2=0.f, aM4=0.f, aM5=0.f, aM8=0.f;
    float aN0=0.f, aN1=0.f, aN2=0.f, aN3=0.f, aN4=0.f,
          aN5=0.f, aN6=0.f, aN7=0.f, aN8=0.f;
    float aP0=0.f, aP1=0.f, aP2=0.f, aP3=0.f, aP4=0.f, aP5=0.f;
    float aR0=0.f, aR1=0.f, aR2=0.f, aR3=0.f, aR4=0.f, aR5=0.f;

    #pragma unroll
    for (int phase = 0; phase < 2; ++phase) {
        // ============ fill: 512 records, 2 per thread ============
        #pragma unroll
        for (int rr = 0; rr < 2; ++rr) {
            int r  = rr*256 + tid;
            int k  = phase*PH + r;
            int gk = b*NN + k;

            float se = 0.f;
            float pk[8];
            #pragma unroll
            for (int c = 0; c < 8; ++c) {
                float f0 = emb[(size_t)b*CC*NN + (size_t)(2*c  )*NN + k];
                float f1 = emb[(size_t)b*CC*NN + (size_t)(2*c+1)*NN + k];
                half2_t hp; hp.x = (_Float16)f0; hp.y = (_Float16)f1;
                pk[c] = __builtin_bit_cast(float, hp);
                float r0 = (float)hp.x, r1 = (float)hp.y;
                se += r0*r0 + r1*r1;
            }
            float u = (float)(k & (WW - 1));
            float v = (float)((k & (NN-1)) >> 5);
            float z = dep[b*NN + k];
            float X = (u - x0) * z * ifx;
            float Y = (v - y0) * z * ify;

            const float4* T4 = (const float4*)(Tm + (size_t)gk * 16);
            float4 t0 = T4[0], t1 = T4[1], t2 = T4[2];
            float Tx = t0.x*X + t0.y*Y + t0.z*z + t0.w;
            float Ty = t1.x*X + t1.y*Y + t1.z*z + t1.w;
            float Tz = t2.x*X + t2.y*Y + t2.z*z + t2.w;
            float di = __builtin_amdgcn_rcpf(Tz);

            float p0 = fx*Tx*di + x0 + rev[(size_t)b*3*NN + 0*NN + k];
            float p1 = fy*Ty*di + y0 + rev[(size_t)b*3*NN + 1*NN + k];
            float p2 = di            + rev[(size_t)b*3*NN + 2*NN + k];
            float w0 = wgt[(size_t)b*3*NN + 0*NN + k];
            float w1 = wgt[(size_t)b*3*NN + 1*NN + k];
            float w2 = wgt[(size_t)b*3*NN + 2*NN + k];

            sE4[r*2 + 0] = make_float4(pk[0], pk[1], pk[2], pk[3]);
            sE4[r*2 + 1] = make_float4(pk[4], pk[5], pk[6], pk[7]);
            sQ0[r] = make_float4(X, Y, z, p0);
            sQ1[r] = make_float4(p1, p2, w0, w1);
            sQ2[r] = make_float2(w2, se);
        }
        __syncthreads();

        // ============ accum: this wave's 256-record chunk, 4 iters ============
        #pragma unroll
        for (int j = 0; j < 4; ++j) {
            int r = h*256 + j*64 + lane;

            float4 ea = sE4[r*2 + 0], eb = sE4[r*2 + 1];
            float4 q0 = sQ0[r], q1 = sQ1[r];
            float2 q2 = sQ2[r];

            float dot = 0.f;
            dot = h2f_dot(ea.x, eih[0], dot);
            dot = h2f_dot(ea.y, eih[1], dot);
            dot = h2f_dot(ea.z, eih[2], dot);
            dot = h2f_dot(ea.w, eih[3], dot);
            dot = h2f_dot(eb.x, eih[4], dot);
            dot = h2f_dot(eb.y, eih[5], dot);
            dot = h2f_dot(eb.z, eih[6], dot);
            dot = h2f_dot(eb.w, eih[7], dot);
            float ssq = fmaxf(sei + q2.y - 2.f*dot, 0.f);
            float aff = __expf(-__builtin_amdgcn_sqrtf(ssq));

            float X = q0.x, Y = q0.y, Z = q0.z;
            float Tx = Tr0.x*X + Tr0.y*Y + Tr0.z*Z + Tr0.w;
            float Ty = Tr1.x*X + Tr1.y*Y + Tr1.z*Z + Tr1.w;
            float Tz = Tr2.x*X + Tr2.y*Y + Tr2.z*Z + Tr2.w;
            float di = __builtin_amdgcn_rcpf(Tz);

            float a =  fx*di;
            float e =  fy*di;
            float uu = a*Tx;
            float vv = e*Ty;
            float r0 = uu + x0 - q0.w;
            float r1 = vv + y0 - q1.x;
            float r2 = di      - q1.y;
            float c = -uu*di;
            float f = -vv*di;
            float g = -di*di;

            float y0v = a*r0;
            float y1v = e*r1;
            float y2v = c*r0 + f*r1 + g*r2;
            aR0 += y0v; aR1 += y1v; aR2 += y2v;
            aR3 += Z*y1v - Y*y2v;
            aR4 += X*y2v - Z*y0v;
            aR5 += Y*y0v - X*y1v;

            float w0 = aff*q1.z, w1 = aff*q1.w, w2 = aff*q2.x;
            float aw = w0*a, ew = w1*e;
            float m00 = aw*a, m02 = aw*c;
            float m11 = ew*e, m12 = ew*f;
            float m22 = w0*c*c + w1*f*f + w2*g*g;
            aM0 += m00; aM2 += m02; aM4 += m11; aM5 += m12; aM8 += m22;

            float n00 = -m02*Y;
            float n01 =  m02*X - m00*Z;
            float n02 =  m00*Y;
            float n10 =  m11*Z - m12*Y;
            float n11 =  m12*X;
            float n12 = -m11*X;
            float n20 =  m12*Z - m22*Y;
            float n21 =  m22*X - m02*Z;
            float n22 =  m02*Y - m12*X;
            aN0 += n00; aN1 += n01; aN2 += n02;
            aN3 += n10; aN4 += n11; aN5 += n12;
            aN6 += n20; aN7 += n21; aN8 += n22;

            aP0 += Z*n10 - Y*n20;
            aP1 += Z*n11 - Y*n21;
            aP2 += Z*n12 - Y*n22;
            aP3 += X*n21 - Z*n01;
            aP4 += X*n22 - Z*n02;
            aP5 += Y*n02 - X*n12;
        }
        __syncthreads();   // protect LDS before next fill
    }

    // ============ butterfly reduce (26) ============
    float acc[26] = { aM0,aM2,aM4,aM5,aM8,
                      aN0,aN1,aN2,aN3,aN4,aN5,aN6,aN7,aN8,
                      aP0,aP1,aP2,aP3,aP4,aP5,
                      aR0,aR1,aR2,aR3,aR4,aR5 };
    #pragma unroll
    for (int off = 32; off > 0; off >>= 1)
        #pragma unroll
        for (int t = 0; t < 26; ++t)
            acc[t] += __shfl_xor(acc[t], off, 64);

    if (lane == 0)
        #pragma unroll
        for (int t = 0; t < 26; ++t) ldsR[wv][t] = acc[t];
    __syncthreads();

    // ============ 2 solver threads per block (tid 0 -> s0, tid 128 -> s1) ====
    if ((tid & 127) != 0) return;
    // this thread is lane 0 of wv = 0 or 2, so its px/Tr/bot match slot s
    int ss = tid >> 7;

    float hv[26];
    #pragma unroll
    for (int t = 0; t < 26; ++t) hv[t] = ldsR[2*ss][t] + ldsR[2*ss+1][t];

    float am[6][6];
    am[0][0]=hv[0]; am[0][1]=0.f;    am[0][2]=hv[1];
    am[1][1]=hv[2]; am[1][2]=hv[3];  am[2][2]=hv[4];
    am[0][3]=hv[5];  am[0][4]=hv[6];  am[0][5]=hv[7];
    am[1][3]=hv[8];  am[1][4]=hv[9];  am[1][5]=hv[10];
    am[2][3]=hv[11]; am[2][4]=hv[12]; am[2][5]=hv[13];
    am[3][3]=hv[14]; am[3][4]=hv[15]; am[3][5]=hv[16];
    am[4][4]=hv[17]; am[4][5]=hv[18]; am[5][5]=hv[19];
    #pragma unroll
    for (int p = 0; p < 6; ++p)
        #pragma unroll
        for (int q = 0; q < p; ++q) am[p][q] = am[q][p];
    float rh[6] = { hv[20], hv[21], hv[22], hv[23], hv[24], hv[25] };

    float L[6][6], dinv[6];
    #pragma unroll
    for (int p = 0; p < 6; ++p) {
        #pragma unroll
        for (int q = 0; q <= p; ++q) {
            float sm = am[p][q];
            #pragma unroll
            for (int r = 0; r < q; ++r) sm -= L[p][r]*L[q][r];
            if (q == p) {
                float sq = __builtin_amdgcn_sqrtf(sm);
                L[p][p] = sq;
                dinv[p] = __builtin_amdgcn_rcpf(sq);
            } else {
                L[p][q] = sm * dinv[q];
            }
        }
    }
    float yv[6];
    #pragma unroll
    for (int p = 0; p < 6; ++p) {
        float sm = rh[p];
        #pragma unroll
        for (int r = 0; r < p; ++r) sm -= L[p][r]*yv[r];
        yv[p] = sm * dinv[p];
    }
    float sol[6];
    #pragma unroll
    for (int pi = 5; pi >= 0; --pi) {
        float sm = yv[pi];
        #pragma unroll
        for (int r = pi + 1; r < 6; ++r) sm -= L[r][pi]*sol[r];
        sol[pi] = sm * dinv[pi];
    }

    float vx = sol[0], vy = sol[1], vz = sol[2];
    float wx = sol[3], wy = sol[4], wz = sol[5];
    float th2 = wx*wx + wy*wy + wz*wz;
    float th  = __builtin_amdgcn_sqrtf(th2);
    float Ae, Be, Ce;
    if (th < 1e-4f) {
        Ae = 1.0f - th2*(1.0f/6.0f);
        Be = 0.5f - th2*(1.0f/24.0f);
        Ce = 1.0f/6.0f - th2*(1.0f/120.0f);
    } else {
        float sn = __sinf(th), cn = __cosf(th);
        float ith = __builtin_amdgcn_rcpf(th), ith2 = ith*ith;
        Ae = sn*ith;
        Be = (1.0f - cn)*ith2;
        Ce = (th - sn)*ith2*ith;
    }
    float Wh[3][3] = {{0.f,-wz, wy},{ wz,0.f,-wx},{-wy, wx,0.f}};
    float W2[3][3] = {{wx*wx - th2, wx*wy,       wx*wz      },
                      {wx*wy,       wy*wy - th2, wy*wz      },
                      {wx*wz,       wy*wz,       wz*wz - th2}};
    float Rd[3][3], Vd[3][3];
    #pragma unroll
    for (int p = 0; p < 3; ++p)
        #pragma unroll
        for (int q = 0; q < 3; ++q) {
            float idq = (p == q) ? 1.0f : 0.0f;
            Rd[p][q] = idq + Ae*Wh[p][q] + Be*W2[p][q];
            Vd[p][q] = idq + Be*Wh[p][q] + Ce*W2[p][q];
        }
    float td[3];
    #pragma unroll
    for (int p = 0; p < 3; ++p)
        td[p] = Vd[p][0]*vx + Vd[p][1]*vy + Vd[p][2]*vz;

    const float4 bot = Tp4[3];
    float* o = out + (size_t)px * 16;
    #pragma unroll
    for (int p = 0; p < 3; ++p) {
        float4 r;
        r.x = Rd[p][0]*Tr0.x + Rd[p][1]*Tr1.x + Rd[p][2]*Tr2.x + td[p]*bot.x;
        r.y = Rd[p][0]*Tr0.y + Rd[p][1]*Tr1.y + Rd[p][2]*Tr2.y + td[p]*bot.y;
        r.z = Rd[p][0]*Tr0.z + Rd[p][1]*Tr1.z + Rd[p][2]*Tr2.z + td[p]*bot.z;
        r.w = Rd[p][0]*Tr0.w + Rd[p][1]*Tr1.w + Rd[p][2]*Tr2.w + td[p]*bot.w;
        *(float4*)(o + p*4) = r;
    }
    *(float4*)(o + 12) = bot;
}

extern "C" void kernel_launch(void* const* d_in, const int* in_sizes, int n_in,
                              void* d_out, int out_size, void* d_ws, size_t ws_size,
                              hipStream_t stream) {
    const float* emb = (const float*)d_in[0];  // (B,C,H,W)
    const float* rev = (const float*)d_in[1];  // (B,3,H,W)
    const float* wgt = (const float*)d_in[2];  // (B,3,H,W)
    const float* dep = (const float*)d_in[3];  // (B,1,H,W)
    const float* pix = (const float*)d_in[4];  // (B,4,4)
    const float* Tm  = (const float*)d_in[5];  // (B,H,W,4,4)
    float* out = (float*)d_out;                // (B,H,W,4,4)

    dse3_mono2<<<NPX/2, 256, 0, stream>>>(emb, rev, wgt, dep, pix, Tm, out);
}

// Round 15
// 22.771 us; speedup vs baseline: 3.0030x; 3.0030x over previous
//
#include <hip/hip_runtime.h>
#include <math.h>

#define BB 2
#define CC 16
#define HH 32
#define WW 32
#define NN (HH*WW)
#define NPX (BB*NN)        // 2048 pixels
#define PH  512            // k-records per LDS phase

// ---------------------------------------------------------------------------
// Single kernel: 256 blocks x 512 thr (8 waves) = 1 block/CU. Block owns 8
// pixels (one per wave). Two LDS phases of 512 k-records:
//   fill (redundant per-block prep, 1 record/thread, coalesced reads, linear
//   LDS writes) -> sync -> each wave accumulates its pixel over the 512
//   records (conflict-free 16B-stride ds_read_b128) -> sync.
// Butterfly(26) gives each wave its complete H; lane-0 f32 solve + compose.
// ---------------------------------------------------------------------------
__global__ __launch_bounds__(512, 2)
void dse3_mono3(const float* __restrict__ emb,
                const float* __restrict__ rev,
                const float* __restrict__ wgt,
                const float* __restrict__ dep,
                const float* __restrict__ pix,
                const float* __restrict__ Tm,
                float* __restrict__ out)
{
    __shared__ float4 sE0[PH], sE1[PH], sE2[PH], sE3[PH], sQ0[PH], sQ1[PH];
    __shared__ float2 sQ2[PH];          // 53.2 KB total

    int tid  = threadIdx.x;
    int lane = tid & 63;
    int wv   = tid >> 6;                // wave 0..7
    int px   = blockIdx.x * 8 + wv;     // this wave's pixel
    int b    = px >> 10;
    int kpx  = px & (NN - 1);

    float fx = pix[b*16 + 0], fy = pix[b*16 + 5];
    float x0 = pix[b*16 + 2], y0 = pix[b*16 + 6];
    float ifx = __builtin_amdgcn_rcpf(fx);
    float ify = __builtin_amdgcn_rcpf(fy);

    // ---- this wave's pixel data (wave-uniform loads) ----
    float ei[16];
    float sei = 0.f;
    #pragma unroll
    for (int c = 0; c < 16; ++c) {
        ei[c] = emb[(size_t)b*CC*NN + (size_t)c*NN + kpx];
        sei += ei[c]*ei[c];
    }
    const float4* Tp4 = (const float4*)(Tm + (size_t)px * 16);
    float4 Tr0 = Tp4[0], Tr1 = Tp4[1], Tr2 = Tp4[2];

    // ---- accumulators (M-factorized, 26) ----
    float aM0=0.f, aM2=0.f, aM4=0.f, aM5=0.f, aM8=0.f;
    float aN0=0.f, aN1=0.f, aN2=0.f, aN3=0.f, aN4=0.f,
          aN5=0.f, aN6=0.f, aN7=0.f, aN8=0.f;
    float aP0=0.f, aP1=0.f, aP2=0.f, aP3=0.f, aP4=0.f, aP5=0.f;
    float aR0=0.f, aR1=0.f, aR2=0.f, aR3=0.f, aR4=0.f, aR5=0.f;

    #pragma unroll
    for (int phase = 0; phase < 2; ++phase) {
        // ============ fill: 512 records, 1 per thread ============
        {
            int r  = tid;
            int k  = phase*PH + r;
            int gk = b*NN + k;

            float se = 0.f;
            float ev[16];
            #pragma unroll
            for (int c = 0; c < 16; ++c) {
                ev[c] = emb[(size_t)b*CC*NN + (size_t)c*NN + k];
                se += ev[c]*ev[c];
            }
            float u = (float)(k & (WW - 1));
            float v = (float)((k & (NN-1)) >> 5);
            float z = dep[b*NN + k];
            float X = (u - x0) * z * ifx;
            float Y = (v - y0) * z * ify;

            const float4* T4 = (const float4*)(Tm + (size_t)gk * 16);
            float4 t0 = T4[0], t1 = T4[1], t2 = T4[2];
            float Tx = t0.x*X + t0.y*Y + t0.z*z + t0.w;
            float Ty = t1.x*X + t1.y*Y + t1.z*z + t1.w;
            float Tz = t2.x*X + t2.y*Y + t2.z*z + t2.w;
            float di = __builtin_amdgcn_rcpf(Tz);

            float p0 = fx*Tx*di + x0 + rev[(size_t)b*3*NN + 0*NN + k];
            float p1 = fy*Ty*di + y0 + rev[(size_t)b*3*NN + 1*NN + k];
            float p2 = di            + rev[(size_t)b*3*NN + 2*NN + k];
            float w0 = wgt[(size_t)b*3*NN + 0*NN + k];
            float w1 = wgt[(size_t)b*3*NN + 1*NN + k];
            float w2 = wgt[(size_t)b*3*NN + 2*NN + k];

            sE0[r] = make_float4(ev[0],  ev[1],  ev[2],  ev[3]);
            sE1[r] = make_float4(ev[4],  ev[5],  ev[6],  ev[7]);
            sE2[r] = make_float4(ev[8],  ev[9],  ev[10], ev[11]);
            sE3[r] = make_float4(ev[12], ev[13], ev[14], ev[15]);
            sQ0[r] = make_float4(X, Y, z, p0);
            sQ1[r] = make_float4(p1, p2, w0, w1);
            sQ2[r] = make_float2(w2, se);
        }
        __syncthreads();

        // ============ accum: 8 iters x 64 lanes ============
        #pragma unroll 2
        for (int j = 0; j < 8; ++j) {
            int r = j*64 + lane;

            float4 k0 = sE0[r], k1 = sE1[r], k2 = sE2[r], k3 = sE3[r];
            float4 q0 = sQ0[r], q1 = sQ1[r];
            float2 q2 = sQ2[r];

            float d0 = k0.x*ei[0]  + k0.y*ei[1]  + k0.z*ei[2]  + k0.w*ei[3];
            float d1 = k1.x*ei[4]  + k1.y*ei[5]  + k1.z*ei[6]  + k1.w*ei[7];
            float d2 = k2.x*ei[8]  + k2.y*ei[9]  + k2.z*ei[10] + k2.w*ei[11];
            float d3 = k3.x*ei[12] + k3.y*ei[13] + k3.z*ei[14] + k3.w*ei[15];
            float dot = (d0 + d1) + (d2 + d3);
            float ssq = fmaxf(sei + q2.y - 2.f*dot, 0.f);
            float aff = __expf(-__builtin_amdgcn_sqrtf(ssq));

            float X = q0.x, Y = q0.y, Z = q0.z;
            float Tx = Tr0.x*X + Tr0.y*Y + Tr0.z*Z + Tr0.w;
            float Ty = Tr1.x*X + Tr1.y*Y + Tr1.z*Z + Tr1.w;
            float Tz = Tr2.x*X + Tr2.y*Y + Tr2.z*Z + Tr2.w;
            float di = __builtin_amdgcn_rcpf(Tz);

            float a =  fx*di;
            float e =  fy*di;
            float uu = a*Tx;
            float vv = e*Ty;
            float r0 = uu + x0 - q0.w;
            float r1 = vv + y0 - q1.x;
            float r2 = di      - q1.y;
            float c = -uu*di;
            float f = -vv*di;
            float g = -di*di;

            float y0v = a*r0;
            float y1v = e*r1;
            float y2v = c*r0 + f*r1 + g*r2;
            aR0 += y0v; aR1 += y1v; aR2 += y2v;
            aR3 += Z*y1v - Y*y2v;
            aR4 += X*y2v - Z*y0v;
            aR5 += Y*y0v - X*y1v;

            float w0 = aff*q1.z, w1 = aff*q1.w, w2 = aff*q2.x;
            float aw = w0*a, ew = w1*e;
            float m00 = aw*a, m02 = aw*c;
            float m11 = ew*e, m12 = ew*f;
            float m22 = w0*c*c + w1*f*f + w2*g*g;
            aM0 += m00; aM2 += m02; aM4 += m11; aM5 += m12; aM8 += m22;

            float n00 = -m02*Y;
            float n01 =  m02*X - m00*Z;
            float n02 =  m00*Y;
            float n10 =  m11*Z - m12*Y;
            float n11 =  m12*X;
            float n12 = -m11*X;
            float n20 =  m12*Z - m22*Y;
            float n21 =  m22*X - m02*Z;
            float n22 =  m02*Y - m12*X;
            aN0 += n00; aN1 += n01; aN2 += n02;
            aN3 += n10; aN4 += n11; aN5 += n12;
            aN6 += n20; aN7 += n21; aN8 += n22;

            aP0 += Z*n10 - Y*n20;
            aP1 += Z*n11 - Y*n21;
            aP2 += Z*n12 - Y*n22;
            aP3 += X*n21 - Z*n01;
            aP4 += X*n22 - Z*n02;
            aP5 += Y*n02 - X*n12;
        }
        __syncthreads();   // protect LDS before next fill
    }

    // ============ butterfly reduce (26) ============
    float acc[26] = { aM0,aM2,aM4,aM5,aM8,
                      aN0,aN1,aN2,aN3,aN4,aN5,aN6,aN7,aN8,
                      aP0,aP1,aP2,aP3,aP4,aP5,
                      aR0,aR1,aR2,aR3,aR4,aR5 };
    #pragma unroll
    for (int off = 32; off > 0; off >>= 1)
        #pragma unroll
        for (int t = 0; t < 26; ++t)
            acc[t] += __shfl_xor(acc[t], off, 64);

    if (lane != 0) return;

    // ============ lane-0 solve (f32) + expmap + compose ============
    float am[6][6];
    am[0][0]=acc[0]; am[0][1]=0.f;    am[0][2]=acc[1];
    am[1][1]=acc[2]; am[1][2]=acc[3]; am[2][2]=acc[4];
    am[0][3]=acc[5];  am[0][4]=acc[6];  am[0][5]=acc[7];
    am[1][3]=acc[8];  am[1][4]=acc[9];  am[1][5]=acc[10];
    am[2][3]=acc[11]; am[2][4]=acc[12]; am[2][5]=acc[13];
    am[3][3]=acc[14]; am[3][4]=acc[15]; am[3][5]=acc[16];
    am[4][4]=acc[17]; am[4][5]=acc[18]; am[5][5]=acc[19];
    #pragma unroll
    for (int p = 0; p < 6; ++p)
        #pragma unroll
        for (int q = 0; q < p; ++q) am[p][q] = am[q][p];
    float rh[6] = { acc[20], acc[21], acc[22], acc[23], acc[24], acc[25] };

    float L[6][6], dinv[6];
    #pragma unroll
    for (int p = 0; p < 6; ++p) {
        #pragma unroll
        for (int q = 0; q <= p; ++q) {
            float sm = am[p][q];
            #pragma unroll
            for (int r = 0; r < q; ++r) sm -= L[p][r]*L[q][r];
            if (q == p) {
                float sq = __builtin_amdgcn_sqrtf(sm);
                L[p][p] = sq;
                dinv[p] = __builtin_amdgcn_rcpf(sq);
            } else {
                L[p][q] = sm * dinv[q];
            }
        }
    }
    float yv[6];
    #pragma unroll
    for (int p = 0; p < 6; ++p) {
        float sm = rh[p];
        #pragma unroll
        for (int r = 0; r < p; ++r) sm -= L[p][r]*yv[r];
        yv[p] = sm * dinv[p];
    }
    float sol[6];
    #pragma unroll
    for (int pi = 5; pi >= 0; --pi) {
        float sm = yv[pi];
        #pragma unroll
        for (int r = pi + 1; r < 6; ++r) sm -= L[r][pi]*sol[r];
        sol[pi] = sm * dinv[pi];
    }

    float vx = sol[0], vy = sol[1], vz = sol[2];
    float wx = sol[3], wy = sol[4], wz = sol[5];
    float th2 = wx*wx + wy*wy + wz*wz;
    float th  = __builtin_amdgcn_sqrtf(th2);
    float Ae, Be, Ce;
    if (th < 1e-4f) {
        Ae = 1.0f - th2*(1.0f/6.0f);
        Be = 0.5f - th2*(1.0f/24.0f);
        Ce = 1.0f/6.0f - th2*(1.0f/120.0f);
    } else {
        float sn = __sinf(th), cn = __cosf(th);
        float ith = __builtin_amdgcn_rcpf(th), ith2 = ith*ith;
        Ae = sn*ith;
        Be = (1.0f - cn)*ith2;
        Ce = (th - sn)*ith2*ith;
    }
    float Wh[3][3] = {{0.f,-wz, wy},{ wz,0.f,-wx},{-wy, wx,0.f}};
    float W2[3][3] = {{wx*wx - th2, wx*wy,       wx*wz      },
                      {wx*wy,       wy*wy - th2, wy*wz      },
                      {wx*wz,       wy*wz,       wz*wz - th2}};
    float Rd[3][3], Vd[3][3];
    #pragma unroll
    for (int p = 0; p < 3; ++p)
        #pragma unroll
        for (int q = 0; q < 3; ++q) {
            float idq = (p == q) ? 1.0f : 0.0f;
            Rd[p][q] = idq + Ae*Wh[p][q] + Be*W2[p][q];
            Vd[p][q] = idq + Be*Wh[p][q] + Ce*W2[p][q];
        }
    float td[3];
    #pragma unroll
    for (int p = 0; p < 3; ++p)
        td[p] = Vd[p][0]*vx + Vd[p][1]*vy + Vd[p][2]*vz;

    const float4 bot = Tp4[3];
    float* o = out + (size_t)px * 16;
    #pragma unroll
    for (int p = 0; p < 3; ++p) {
        float4 r;
        r.x = Rd[p][0]*Tr0.x + Rd[p][1]*Tr1.x + Rd[p][2]*Tr2.x + td[p]*bot.x;
        r.y = Rd[p][0]*Tr0.y + Rd[p][1]*Tr1.y + Rd[p][2]*Tr2.y + td[p]*bot.y;
        r.z = Rd[p][0]*Tr0.z + Rd[p][1]*Tr1.z + Rd[p][2]*Tr2.z + td[p]*bot.z;
        r.w = Rd[p][0]*Tr0.w + Rd[p][1]*Tr1.w + Rd[p][2]*Tr2.w + td[p]*bot.w;
        *(float4*)(o + p*4) = r;
    }
    *(float4*)(o + 12) = bot;
}

extern "C" void kernel_launch(void* const* d_in, const int* in_sizes, int n_in,
                              void* d_out, int out_size, void* d_ws, size_t ws_size,
                              hipStream_t stream) {
    const float* emb = (const float*)d_in[0];  // (B,C,H,W)
    const float* rev = (const float*)d_in[1];  // (B,3,H,W)
    const float* wgt = (const float*)d_in[2];  // (B,3,H,W)
    const float* dep = (const float*)d_in[3];  // (B,1,H,W)
    const float* pix = (const float*)d_in[4];  // (B,4,4)
    const float* Tm  = (const float*)d_in[5];  // (B,H,W,4,4)
    float* out = (float*)d_out;                // (B,H,W,4,4)

    dse3_mono3<<<NPX/8, 512, 0, stream>>>(emb, rev, wgt, dep, pix, Tm, out);
}